// Round 5
// baseline (1124.104 us; speedup 1.0000x reference)
//
#include <hip/hip_runtime.h>
#include <hip/hip_bf16.h>
#include <stdint.h>

// Problem constants (fixed by the reference)
#define NN   50000
#define RR   50
#define BB   30
#define DIN  64
#define EE   1000000
#define KTOT (BB*DIN + DIN)   // 1984 = 62*32
#define NBW  16               // nodes per workgroup (16-row MFMA tile); 50000 = 3125*16 exactly
#define ROWE (KTOT + 8)       // padded LDS row: 1992 elems (3984 B)
#define CPAD 32               // comp row padded 30 -> 32 floats

typedef __attribute__((ext_vector_type(8))) short short8;
typedef __attribute__((ext_vector_type(4))) float floatx4;

#define RFL(x) __builtin_amdgcn_readfirstlane(x)

// ---------------- preprocessing: counting sort of edges by dst ----------------

__global__ void k_hist(const int* __restrict__ dst, const int* __restrict__ et,
                       int* __restrict__ cnt, int* __restrict__ dcount) {
    int e = blockIdx.x * 256 + threadIdx.x;
    if (e < EE) {
        int d = dst[e], r = et[e];
        atomicAdd(&cnt[d * RR + r], 1);
        atomicAdd(&dcount[d], 1);
    }
}

__global__ void k_scan1(const int* __restrict__ dcount, int* __restrict__ doff,
                        int* __restrict__ bsum) {
    __shared__ int sh[256];
    int t = threadIdx.x;
    int i = blockIdx.x * 256 + t;
    int v = (i < NN) ? dcount[i] : 0;
    sh[t] = v;
    __syncthreads();
    for (int s = 1; s < 256; s <<= 1) {
        int add = (t >= s) ? sh[t - s] : 0;
        __syncthreads();
        sh[t] += add;
        __syncthreads();
    }
    int incl = sh[t];
    if (i < NN) doff[i] = incl - v;
    if (t == 255) bsum[blockIdx.x] = incl;
}

__global__ void k_scan2(int* __restrict__ bsum, int nbv) {
    __shared__ int sh[256];
    int t = threadIdx.x;
    int v = (t < nbv) ? bsum[t] : 0;
    sh[t] = v;
    __syncthreads();
    for (int s = 1; s < 256; s <<= 1) {
        int add = (t >= s) ? sh[t - s] : 0;
        __syncthreads();
        sh[t] += add;
        __syncthreads();
    }
    if (t < nbv) bsum[t] = sh[t] - v;
}

__global__ void k_scan3(int* __restrict__ doff, const int* __restrict__ bsum) {
    int i = blockIdx.x * 256 + threadIdx.x;
    if (i < NN) doff[i] += bsum[blockIdx.x];
}

__global__ void k_scatter(const int* __restrict__ src, const int* __restrict__ dst,
                          const int* __restrict__ et, const int* __restrict__ cnt,
                          const int* __restrict__ doff, int* __restrict__ cursor,
                          int4* __restrict__ epack) {
    int e = blockIdx.x * 256 + threadIdx.x;
    if (e < EE) {
        int d = dst[e], r = et[e], s = src[e];
        int p = doff[d] + atomicAdd(&cursor[d], 1);
        float a = 1.0f / (float)cnt[d * RR + r];
        epack[p] = make_int4(s, r, __float_as_int(a), 0);
    }
}

__global__ void k_cast_x(const float* __restrict__ x, __hip_bfloat16* __restrict__ h) {
    int i = blockIdx.x * 256 + threadIdx.x;
    if (i < NN * DIN) h[i] = __float2bfloat16(x[i]);
}

// all 3 layers' comp [R,30] fp32 -> padded [3][R,32] fp32
__global__ void k_prep_comp3(const float* __restrict__ c0, const float* __restrict__ c1,
                             const float* __restrict__ c2, float* __restrict__ cp) {
    int idx = blockIdx.x * 256 + threadIdx.x;
    if (idx < 3 * RR * CPAD) {
        int l = idx / (RR * CPAD);
        int rem = idx - l * (RR * CPAD);
        int r = rem / CPAD, i = rem - r * CPAD;
        const float* c = (l == 0) ? c0 : (l == 1) ? c1 : c2;
        cp[idx] = (i < BB) ? c[r * BB + i] : 0.f;
    }
}

// all 3 layers' transposed bf16 weights:
// wt rows [0,64): layer0; [64,128): layer1; [128,144): layer2 (dout=8, 16 padded rows)
__global__ void k_prep_w3(const float* __restrict__ b0, const float* __restrict__ r0,
                          const float* __restrict__ b1, const float* __restrict__ r1,
                          const float* __restrict__ b2, const float* __restrict__ r2,
                          short* __restrict__ wt) {
    int idx = blockIdx.x * 256 + threadIdx.x;
    if (idx >= 144 * KTOT) return;
    int row = idx / KTOT, k = idx - row * KTOT;
    const float* bs; const float* rt; int o, dout;
    if (row < 64)       { bs = b0; rt = r0; o = row;        dout = 64; }
    else if (row < 128) { bs = b1; rt = r1; o = row - 64;   dout = 64; }
    else                { bs = b2; rt = r2; o = row - 128;  dout = 8;  }
    float v = 0.f;
    if (o < dout)
        v = (k < BB * DIN) ? bs[k * dout + o] : rt[(k - BB * DIN) * dout + o];
    __hip_bfloat16 hb = __float2bfloat16(v);
    wt[idx] = *reinterpret_cast<const short*>(&hb);
}

// ---------------- fused per-layer kernel ----------------
// 512 threads = 8 waves. Phase 1: wave wv owns nodes wv*2, wv*2+1; 3-stage
// software pipeline (records 2 chunks ahead, gathers 1 chunk ahead of FMA).
// Phase 2: 8 waves split the K=62-step MFMA loop; partials reduced through LDS.
template <int DOUT, bool RELU>
__global__ __launch_bounds__(512, 4)
void k_fused(const __hip_bfloat16* __restrict__ xin,
             const int4* __restrict__ epack,
             const int* __restrict__ doff, const int* __restrict__ dcount,
             const float* __restrict__ compP,    // [R, 32] fp32 padded
             const short* __restrict__ Wt,       // [DPAD][KTOT] bf16 (transposed)
             const float* __restrict__ bias,     // [DOUT]
             void* __restrict__ outp) {
    __shared__ __align__(16) char smem_raw[NBW * ROWE * 2];   // 63744 B
    auto t_tile = reinterpret_cast<__hip_bfloat16(*)[ROWE]>(smem_raw);
    const int tid  = threadIdx.x;
    const int lane = tid & 63;
    const int wv   = RFL(tid >> 6);          // 0..7
    const int node0 = blockIdx.x * NBW;

    // ---- phase 1: 2 nodes per wave, software-pipelined ----
    {
        const int jA = wv * 2, jB = jA + 1;
        const int nA = node0 + jA, nB = node0 + jB;
        floatx4 accA[8], accB[8];
#pragma unroll
        for (int u = 0; u < 8; ++u) {
            accA[u] = (floatx4){0.f, 0.f, 0.f, 0.f};
            accB[u] = (floatx4){0.f, 0.f, 0.f, 0.f};
        }
        const int begA = RFL(doff[nA]), cntA = RFL(dcount[nA]);
        const int begB = RFL(doff[nB]), cntB = RFL(dcount[nB]);
        const int mnc = (cntA < cntB ? cntA : cntB) & ~1;

        // G stage: gathered values pending FMA
        float gA0, gA1, gB0, gB1;
        float pA0, pA1, pB0, pB1;               // alpha
        const floatx4 *qA0, *qA1, *qB0, *qB1;   // comp rows
        // R2 stage: records for chunk i+2
        int   rsA0, rsA1, rsB0, rsB1;
        float raA0, raA1, raB0, raB1;
        const floatx4 *rcA0, *rcA1, *rcB0, *rcB1;

        if (mnc >= 2) {
            {   // chunk 0: load records, issue gathers
                int4 a0 = epack[begA], a1 = epack[begA + 1];
                int4 b0 = epack[begB], b1 = epack[begB + 1];
                int sA0 = RFL(a0.x), sA1 = RFL(a1.x), sB0 = RFL(b0.x), sB1 = RFL(b1.x);
                pA0 = __int_as_float(RFL(a0.z)); pA1 = __int_as_float(RFL(a1.z));
                pB0 = __int_as_float(RFL(b0.z)); pB1 = __int_as_float(RFL(b1.z));
                qA0 = (const floatx4*)(compP + RFL(a0.y) * CPAD);
                qA1 = (const floatx4*)(compP + RFL(a1.y) * CPAD);
                qB0 = (const floatx4*)(compP + RFL(b0.y) * CPAD);
                qB1 = (const floatx4*)(compP + RFL(b1.y) * CPAD);
                gA0 = __bfloat162float(xin[sA0 * DIN + lane]);
                gA1 = __bfloat162float(xin[sA1 * DIN + lane]);
                gB0 = __bfloat162float(xin[sB0 * DIN + lane]);
                gB1 = __bfloat162float(xin[sB1 * DIN + lane]);
            }
            {   // chunk 2 records (clamped)
                const int i2 = (2 <= mnc - 2) ? 2 : 0;
                int4 a0 = epack[begA + i2], a1 = epack[begA + i2 + 1];
                int4 b0 = epack[begB + i2], b1 = epack[begB + i2 + 1];
                rsA0 = RFL(a0.x); rsA1 = RFL(a1.x); rsB0 = RFL(b0.x); rsB1 = RFL(b1.x);
                raA0 = __int_as_float(RFL(a0.z)); raA1 = __int_as_float(RFL(a1.z));
                raB0 = __int_as_float(RFL(b0.z)); raB1 = __int_as_float(RFL(b1.z));
                rcA0 = (const floatx4*)(compP + RFL(a0.y) * CPAD);
                rcA1 = (const floatx4*)(compP + RFL(a1.y) * CPAD);
                rcB0 = (const floatx4*)(compP + RFL(b0.y) * CPAD);
                rcB1 = (const floatx4*)(compP + RFL(b1.y) * CPAD);
            }
            for (int i = 0; i + 4 <= mnc; i += 2) {
                // issue gathers for chunk i+2 (records already in regs)
                float nA0 = __bfloat162float(xin[rsA0 * DIN + lane]);
                float nA1 = __bfloat162float(xin[rsA1 * DIN + lane]);
                float nB0 = __bfloat162float(xin[rsB0 * DIN + lane]);
                float nB1 = __bfloat162float(xin[rsB1 * DIN + lane]);
                float naA0 = raA0, naA1 = raA1, naB0 = raB0, naB1 = raB1;
                const floatx4 *nqA0 = rcA0, *nqA1 = rcA1, *nqB0 = rcB0, *nqB1 = rcB1;
                // prefetch records for chunk i+4 (clamped)
                {
                    int i4 = i + 4; if (i4 > mnc - 2) i4 = mnc - 2;
                    int4 a0 = epack[begA + i4], a1 = epack[begA + i4 + 1];
                    int4 b0 = epack[begB + i4], b1 = epack[begB + i4 + 1];
                    rsA0 = RFL(a0.x); rsA1 = RFL(a1.x); rsB0 = RFL(b0.x); rsB1 = RFL(b1.x);
                    raA0 = __int_as_float(RFL(a0.z)); raA1 = __int_as_float(RFL(a1.z));
                    raB0 = __int_as_float(RFL(b0.z)); raB1 = __int_as_float(RFL(b1.z));
                    rcA0 = (const floatx4*)(compP + RFL(a0.y) * CPAD);
                    rcA1 = (const floatx4*)(compP + RFL(a1.y) * CPAD);
                    rcB0 = (const floatx4*)(compP + RFL(b0.y) * CPAD);
                    rcB1 = (const floatx4*)(compP + RFL(b1.y) * CPAD);
                }
                // FMA chunk i (gathers issued one iteration ago)
                {
                    const float vA0 = gA0 * pA0, vA1 = gA1 * pA1;
                    const float vB0 = gB0 * pB0, vB1 = gB1 * pB1;
                    const floatx4 wA0 = {vA0, vA0, vA0, vA0};
                    const floatx4 wA1 = {vA1, vA1, vA1, vA1};
                    const floatx4 wB0 = {vB0, vB0, vB0, vB0};
                    const floatx4 wB1 = {vB1, vB1, vB1, vB1};
#pragma unroll
                    for (int u = 0; u < 8; ++u) accA[u] = qA0[u] * wA0 + accA[u];
#pragma unroll
                    for (int u = 0; u < 8; ++u) accB[u] = qB0[u] * wB0 + accB[u];
#pragma unroll
                    for (int u = 0; u < 8; ++u) accA[u] = qA1[u] * wA1 + accA[u];
#pragma unroll
                    for (int u = 0; u < 8; ++u) accB[u] = qB1[u] * wB1 + accB[u];
                }
                // rotate
                gA0 = nA0; gA1 = nA1; gB0 = nB0; gB1 = nB1;
                pA0 = naA0; pA1 = naA1; pB0 = naB0; pB1 = naB1;
                qA0 = nqA0; qA1 = nqA1; qB0 = nqB0; qB1 = nqB1;
            }
            {   // FMA final chunk (mnc-2)
                const float vA0 = gA0 * pA0, vA1 = gA1 * pA1;
                const float vB0 = gB0 * pB0, vB1 = gB1 * pB1;
                const floatx4 wA0 = {vA0, vA0, vA0, vA0};
                const floatx4 wA1 = {vA1, vA1, vA1, vA1};
                const floatx4 wB0 = {vB0, vB0, vB0, vB0};
                const floatx4 wB1 = {vB1, vB1, vB1, vB1};
#pragma unroll
                for (int u = 0; u < 8; ++u) accA[u] = qA0[u] * wA0 + accA[u];
#pragma unroll
                for (int u = 0; u < 8; ++u) accB[u] = qB0[u] * wB0 + accB[u];
#pragma unroll
                for (int u = 0; u < 8; ++u) accA[u] = qA1[u] * wA1 + accA[u];
#pragma unroll
                for (int u = 0; u < 8; ++u) accB[u] = qB1[u] * wB1 + accB[u];
            }
        }
        // tails (serial)
        for (int e = mnc; e < cntA; ++e) {
            int4 a0 = epack[begA + e];
            const int s = RFL(a0.x);
            const float al = __int_as_float(RFL(a0.z));
            const floatx4* c = (const floatx4*)(compP + RFL(a0.y) * CPAD);
            const float xv = __bfloat162float(xin[s * DIN + lane]) * al;
            const floatx4 w = {xv, xv, xv, xv};
#pragma unroll
            for (int u = 0; u < 8; ++u) accA[u] = c[u] * w + accA[u];
        }
        for (int e = mnc; e < cntB; ++e) {
            int4 b0 = epack[begB + e];
            const int s = RFL(b0.x);
            const float al = __int_as_float(RFL(b0.z));
            const floatx4* c = (const floatx4*)(compP + RFL(b0.y) * CPAD);
            const float xv = __bfloat162float(xin[s * DIN + lane]) * al;
            const floatx4 w = {xv, xv, xv, xv};
#pragma unroll
            for (int u = 0; u < 8; ++u) accB[u] = c[u] * w + accB[u];
        }

        const float xsA = __bfloat162float(xin[nA * DIN + lane]);
        const float xsB = __bfloat162float(xin[nB * DIN + lane]);
#pragma unroll
        for (int b = 0; b < BB; ++b) {
            t_tile[jA][b * DIN + lane] = __float2bfloat16(accA[b >> 2][b & 3]);
            t_tile[jB][b * DIN + lane] = __float2bfloat16(accB[b >> 2][b & 3]);
        }
        t_tile[jA][BB * DIN + lane] = __float2bfloat16(xsA);
        t_tile[jB][BB * DIN + lane] = __float2bfloat16(xsB);
    }
    __syncthreads();

    // ---- phase 2: MFMA 16x16x32 bf16, K = 1984, split across 8 waves ----
    const int m = lane & 15;
    const int q = lane >> 4;
    int kk0, nsteps, col_base;
    if (DOUT == 64) {
        kk0 = (wv >> 2) * 31; nsteps = 31; col_base = (wv & 3) * 16;
    } else {
        kk0 = wv * 8; nsteps = (wv == 7) ? 6 : 8; col_base = 0;
    }
    const __hip_bfloat16* arow = &t_tile[m][q * 8];
    const short* brow = Wt + (size_t)(col_base + m) * KTOT + q * 8;

    floatx4 acc0 = {0.f, 0.f, 0.f, 0.f};
    floatx4 acc1 = {0.f, 0.f, 0.f, 0.f};
    int s = 0;
    for (; s + 2 <= nsteps; s += 2) {
        const int kk = kk0 + s;
        short8 a0 = *reinterpret_cast<const short8*>(arow + kk * 32);
        short8 b0 = *reinterpret_cast<const short8*>(brow + kk * 32);
        short8 a1 = *reinterpret_cast<const short8*>(arow + (kk + 1) * 32);
        short8 b1 = *reinterpret_cast<const short8*>(brow + (kk + 1) * 32);
        acc0 = __builtin_amdgcn_mfma_f32_16x16x32_bf16(a0, b0, acc0, 0, 0, 0);
        acc1 = __builtin_amdgcn_mfma_f32_16x16x32_bf16(a1, b1, acc1, 0, 0, 0);
    }
    if (s < nsteps) {
        const int kk = kk0 + s;
        short8 a0 = *reinterpret_cast<const short8*>(arow + kk * 32);
        short8 b0 = *reinterpret_cast<const short8*>(brow + kk * 32);
        acc0 = __builtin_amdgcn_mfma_f32_16x16x32_bf16(a0, b0, acc0, 0, 0, 0);
    }
    floatx4 P = acc0 + acc1;

    __syncthreads();                       // all t_tile reads done
    float* red = (float*)smem_raw;         // reuse LDS; stride-6 layout kills 8-way conflicts

    if (DOUT == 64) {
        if (wv >= 4) {
            const int off = ((wv - 4) * 64 + lane) * 6;
            red[off] = P[0]; red[off + 1] = P[1]; red[off + 2] = P[2]; red[off + 3] = P[3];
        }
        __syncthreads();
        if (wv < 4) {
            const int off = (wv * 64 + lane) * 6;
            P[0] += red[off]; P[1] += red[off + 1]; P[2] += red[off + 2]; P[3] += red[off + 3];
            const int o = col_base + m;
            const float bi = bias[o];
#pragma unroll
            for (int r = 0; r < 4; ++r) {
                const int n = node0 + q * 4 + r;
                float v = P[r] + bi;
                if (RELU) {
                    v = fmaxf(v, 0.f);
                    reinterpret_cast<__hip_bfloat16*>(outp)[(size_t)n * DOUT + o] =
                        __float2bfloat16(v);
                } else {
                    reinterpret_cast<float*>(outp)[(size_t)n * DOUT + o] = v;
                }
            }
        }
    } else {
        if (wv > 0) {
            const int off = ((wv - 1) * 64 + lane) * 6;
            red[off] = P[0]; red[off + 1] = P[1]; red[off + 2] = P[2]; red[off + 3] = P[3];
        }
        __syncthreads();
        if (wv == 0) {
#pragma unroll
            for (int w = 0; w < 7; ++w) {
                const int off = (w * 64 + lane) * 6;
                P[0] += red[off]; P[1] += red[off + 1];
                P[2] += red[off + 2]; P[3] += red[off + 3];
            }
            if (m < DOUT) {
                const int o = m;
                const float bi = bias[o];
#pragma unroll
                for (int r = 0; r < 4; ++r) {
                    const int n = node0 + q * 4 + r;
                    reinterpret_cast<float*>(outp)[(size_t)n * DOUT + o] = P[r] + bi;
                }
            }
        }
    }
}

// ---------------- log_softmax over C=8 ----------------
__global__ void k_lsm(const float* __restrict__ pre, float* __restrict__ out) {
    int n = blockIdx.x * 256 + threadIdx.x;
    if (n < NN) {
        float v[8];
        float mx = -1e30f;
#pragma unroll
        for (int c = 0; c < 8; ++c) { v[c] = pre[n * 8 + c]; mx = fmaxf(mx, v[c]); }
        float s = 0.f;
#pragma unroll
        for (int c = 0; c < 8; ++c) s += expf(v[c] - mx);
        float ls = logf(s);
#pragma unroll
        for (int c = 0; c < 8; ++c) out[n * 8 + c] = v[c] - mx - ls;
    }
}

// ---------------- launch ----------------
extern "C" void kernel_launch(void* const* d_in, const int* in_sizes, int n_in,
                              void* d_out, int out_size, void* d_ws, size_t ws_size,
                              hipStream_t stream) {
    const float* x     = (const float*)d_in[0];
    const int*   eidx  = (const int*)d_in[1];
    const int*   etype = (const int*)d_in[2];
    const float* bases0 = (const float*)d_in[3];
    const float* comp0  = (const float*)d_in[4];
    const float* root0  = (const float*)d_in[5];
    const float* bias0  = (const float*)d_in[6];
    const float* bases1 = (const float*)d_in[7];
    const float* comp1  = (const float*)d_in[8];
    const float* root1  = (const float*)d_in[9];
    const float* bias1  = (const float*)d_in[10];
    const float* bases2 = (const float*)d_in[11];
    const float* comp2  = (const float*)d_in[12];
    const float* root2  = (const float*)d_in[13];
    const float* bias2  = (const float*)d_in[14];
    const int* srcp = eidx;
    const int* dstp = eidx + EE;

    char* p = (char*)d_ws;
    auto carve = [&](size_t bytes) -> char* {
        char* r = p;
        p += (bytes + 255) & ~(size_t)255;
        return r;
    };
    int*  cnt    = (int*)carve((size_t)NN * RR * sizeof(int));   // 10 MB
    int*  dcount = (int*)carve((size_t)NN * sizeof(int));
    int*  cursor = (int*)carve((size_t)NN * sizeof(int));
    int*  doff   = (int*)carve((size_t)NN * sizeof(int));
    int*  bsum   = (int*)carve(256 * sizeof(int));
    int4* epack  = (int4*)carve((size_t)EE * sizeof(int4));      // 16 MB
    __hip_bfloat16* h0 = (__hip_bfloat16*)carve((size_t)NN * DIN * 2);
    __hip_bfloat16* h1 = (__hip_bfloat16*)carve((size_t)NN * DIN * 2);
    __hip_bfloat16* h2 = (__hip_bfloat16*)carve((size_t)NN * DIN * 2);
    float* pre = (float*)carve((size_t)NN * 8 * sizeof(float));
    short* wtA = (short*)carve((size_t)144 * KTOT * sizeof(short));  // 3 layers stacked
    float* cpA = (float*)carve((size_t)3 * RR * CPAD * sizeof(float));

    // cnt, dcount, cursor are adjacent in the carve order -> one memset
    hipMemsetAsync(cnt, 0, (size_t)NN * (RR + 2) * sizeof(int) + 512, stream);

    const int EB = (EE + 255) / 256;   // 3907
    const int NB = (NN + 255) / 256;   // 196
    k_hist<<<EB, 256, 0, stream>>>(dstp, etype, cnt, dcount);
    k_scan1<<<NB, 256, 0, stream>>>(dcount, doff, bsum);
    k_scan2<<<1, 256, 0, stream>>>(bsum, NB);
    k_scan3<<<NB, 256, 0, stream>>>(doff, bsum);
    k_scatter<<<EB, 256, 0, stream>>>(srcp, dstp, etype, cnt, doff, cursor, epack);
    k_cast_x<<<(NN * DIN + 255) / 256, 256, 0, stream>>>(x, h0);
    k_prep_comp3<<<(3 * RR * CPAD + 255) / 256, 256, 0, stream>>>(comp0, comp1, comp2, cpA);
    k_prep_w3<<<(144 * KTOT + 255) / 256, 256, 0, stream>>>(bases0, root0, bases1, root1,
                                                            bases2, root2, wtA);

    short* wt0 = wtA;
    short* wt1 = wtA + (size_t)64 * KTOT;
    short* wt2 = wtA + (size_t)128 * KTOT;
    float* cp0 = cpA;
    float* cp1 = cpA + RR * CPAD;
    float* cp2 = cpA + 2 * RR * CPAD;

    const int NF = (NN + NBW - 1) / NBW;   // 3125
    k_fused<64, true ><<<NF, 512, 0, stream>>>(h0, epack, doff, dcount, cp0, wt0, bias0, (void*)h1);
    k_fused<64, true ><<<NF, 512, 0, stream>>>(h1, epack, doff, dcount, cp1, wt1, bias1, (void*)h2);
    k_fused<8,  false><<<NF, 512, 0, stream>>>(h2, epack, doff, dcount, cp2, wt2, bias2, (void*)pre);
    k_lsm<<<NB, 256, 0, stream>>>(pre, (float*)d_out);
}

// Round 6
// 612.573 us; speedup vs baseline: 1.8351x; 1.8351x over previous
//
#include <hip/hip_runtime.h>
#include <hip/hip_bf16.h>
#include <stdint.h>

// Problem constants (fixed by the reference)
#define NN   50000
#define RR   50
#define BB   30
#define DIN  64
#define EE   1000000
#define KTOT (BB*DIN + DIN)   // 1984 = 62*32
#define NBW  16               // nodes per workgroup; 50000 = 3125*16 exactly
#define ROWE (KTOT + 8)       // padded LDS row: 1992 elems (3984 B)
#define CPAD 32               // comp row padded 30 -> 32 floats

typedef __attribute__((ext_vector_type(8))) short short8;
typedef __attribute__((ext_vector_type(4))) float floatx4;

#define RFL(x) __builtin_amdgcn_readfirstlane(x)

// ---------------- preprocessing: counting sort of edges by dst ----------------

__global__ void k_hist(const int* __restrict__ dst, const int* __restrict__ et,
                       int* __restrict__ cnt, int* __restrict__ dcount) {
    int e = blockIdx.x * 256 + threadIdx.x;
    if (e < EE) {
        int d = dst[e], r = et[e];
        atomicAdd(&cnt[d * RR + r], 1);
        atomicAdd(&dcount[d], 1);
    }
}

__global__ void k_scan1(const int* __restrict__ dcount, int* __restrict__ doff,
                        int* __restrict__ bsum) {
    __shared__ int sh[256];
    int t = threadIdx.x;
    int i = blockIdx.x * 256 + t;
    int v = (i < NN) ? dcount[i] : 0;
    sh[t] = v;
    __syncthreads();
    for (int s = 1; s < 256; s <<= 1) {
        int add = (t >= s) ? sh[t - s] : 0;
        __syncthreads();
        sh[t] += add;
        __syncthreads();
    }
    int incl = sh[t];
    if (i < NN) doff[i] = incl - v;
    if (t == 255) bsum[blockIdx.x] = incl;
}

__global__ void k_scan2(int* __restrict__ bsum, int nbv) {
    __shared__ int sh[256];
    int t = threadIdx.x;
    int v = (t < nbv) ? bsum[t] : 0;
    sh[t] = v;
    __syncthreads();
    for (int s = 1; s < 256; s <<= 1) {
        int add = (t >= s) ? sh[t - s] : 0;
        __syncthreads();
        sh[t] += add;
        __syncthreads();
    }
    if (t < nbv) bsum[t] = sh[t] - v;
}

__global__ void k_scan3(int* __restrict__ doff, const int* __restrict__ bsum) {
    int i = blockIdx.x * 256 + threadIdx.x;
    if (i < NN) doff[i] += bsum[blockIdx.x];
}

__global__ void k_scatter(const int* __restrict__ src, const int* __restrict__ dst,
                          const int* __restrict__ et, const int* __restrict__ cnt,
                          const int* __restrict__ doff, int* __restrict__ cursor,
                          int4* __restrict__ epack) {
    int e = blockIdx.x * 256 + threadIdx.x;
    if (e < EE) {
        int d = dst[e], r = et[e], s = src[e];
        int p = doff[d] + atomicAdd(&cursor[d], 1);
        float a = 1.0f / (float)cnt[d * RR + r];
        epack[p] = make_int4(s, r, __float_as_int(a), 0);
    }
}

__global__ void k_cast_x(const float* __restrict__ x, __hip_bfloat16* __restrict__ h) {
    int i = blockIdx.x * 256 + threadIdx.x;
    if (i < NN * DIN) h[i] = __float2bfloat16(x[i]);
}

// all 3 layers' comp [R,30] fp32 -> padded [3][R,32] fp32
__global__ void k_prep_comp3(const float* __restrict__ c0, const float* __restrict__ c1,
                             const float* __restrict__ c2, float* __restrict__ cp) {
    int idx = blockIdx.x * 256 + threadIdx.x;
    if (idx < 3 * RR * CPAD) {
        int l = idx / (RR * CPAD);
        int rem = idx - l * (RR * CPAD);
        int r = rem / CPAD, i = rem - r * CPAD;
        const float* c = (l == 0) ? c0 : (l == 1) ? c1 : c2;
        cp[idx] = (i < BB) ? c[r * BB + i] : 0.f;
    }
}

// all 3 layers' transposed bf16 weights:
// wt rows [0,64): layer0; [64,128): layer1; [128,144): layer2 (dout=8, 16 padded rows)
__global__ void k_prep_w3(const float* __restrict__ b0, const float* __restrict__ r0,
                          const float* __restrict__ b1, const float* __restrict__ r1,
                          const float* __restrict__ b2, const float* __restrict__ r2,
                          short* __restrict__ wt) {
    int idx = blockIdx.x * 256 + threadIdx.x;
    if (idx >= 144 * KTOT) return;
    int row = idx / KTOT, k = idx - row * KTOT;
    const float* bs; const float* rt; int o, dout;
    if (row < 64)       { bs = b0; rt = r0; o = row;        dout = 64; }
    else if (row < 128) { bs = b1; rt = r1; o = row - 64;   dout = 64; }
    else                { bs = b2; rt = r2; o = row - 128;  dout = 8;  }
    float v = 0.f;
    if (o < dout)
        v = (k < BB * DIN) ? bs[k * dout + o] : rt[(k - BB * DIN) * dout + o];
    __hip_bfloat16 hb = __float2bfloat16(v);
    wt[idx] = *reinterpret_cast<const short*>(&hb);
}

// ---------------- fused per-layer kernel ----------------
// 1024 threads = 16 waves, 2 blocks/CU (LDS-capped) -> 32 waves/CU.
// Phase 1: wave wv owns node wv; simple unroll-2 edge walk (R4 structure —
//   NO manual multi-stage pipeline: that spilled to scratch in R5, WRITE_SIZE
//   6MB -> 300MB).
// Phase 2: 16 waves = 4 col-tiles x 4 K-parts (DOUT=64) or 16 K-parts (DOUT=8);
//   partials reduced through LDS with stride-6 layout (2-way max).
template <int DOUT, bool RELU>
__global__ __launch_bounds__(1024, 8)
void k_fused(const __hip_bfloat16* __restrict__ xin,
             const int4* __restrict__ epack,
             const int* __restrict__ doff, const int* __restrict__ dcount,
             const float* __restrict__ compP,    // [R, 32] fp32 padded
             const short* __restrict__ Wt,       // [DPAD][KTOT] bf16 (transposed)
             const float* __restrict__ bias,     // [DOUT]
             void* __restrict__ outp) {
    __shared__ __align__(16) char smem_raw[NBW * ROWE * 2];   // 63744 B
    auto t_tile = reinterpret_cast<__hip_bfloat16(*)[ROWE]>(smem_raw);
    const int tid  = threadIdx.x;
    const int lane = tid & 63;
    const int wv   = RFL(tid >> 6);          // 0..15
    const int node0 = blockIdx.x * NBW;

    // ---- phase 1: one node per wave, unroll-2 ----
    {
        const int j = wv;
        const int n = node0 + j;              // always < NN (50000 = 3125*16)
        floatx4 acc[8];
#pragma unroll
        for (int u = 0; u < 8; ++u) acc[u] = (floatx4){0.f, 0.f, 0.f, 0.f};
        const int beg = RFL(doff[n]), cnt = RFL(dcount[n]);
        int e = 0;
        for (; e + 2 <= cnt; e += 2) {
            int4 ep0 = epack[beg + e];
            int4 ep1 = epack[beg + e + 1];
            const int s0 = RFL(ep0.x), r0 = RFL(ep0.y);
            const int s1 = RFL(ep1.x), r1 = RFL(ep1.y);
            const float a0 = __int_as_float(RFL(ep0.z));
            const float a1 = __int_as_float(RFL(ep1.z));
            // issue both gathers before the FMA blocks
            const float x0 = __bfloat162float(xin[s0 * DIN + lane]) * a0;
            const float x1 = __bfloat162float(xin[s1 * DIN + lane]) * a1;
            const floatx4* c0 = (const floatx4*)(compP + r0 * CPAD);
            const floatx4* c1 = (const floatx4*)(compP + r1 * CPAD);
            const floatx4 v0 = {x0, x0, x0, x0};
            const floatx4 v1 = {x1, x1, x1, x1};
#pragma unroll
            for (int u = 0; u < 8; ++u) acc[u] = c0[u] * v0 + acc[u];
#pragma unroll
            for (int u = 0; u < 8; ++u) acc[u] = c1[u] * v1 + acc[u];
        }
        if (e < cnt) {
            int4 ep = epack[beg + e];
            const int s = RFL(ep.x), r = RFL(ep.y);
            const float a = __int_as_float(RFL(ep.z));
            const float xv = __bfloat162float(xin[s * DIN + lane]) * a;
            const floatx4* c = (const floatx4*)(compP + r * CPAD);
            const floatx4 w = {xv, xv, xv, xv};
#pragma unroll
            for (int u = 0; u < 8; ++u) acc[u] = c[u] * w + acc[u];
        }
        const float xself = __bfloat162float(xin[n * DIN + lane]);
#pragma unroll
        for (int b = 0; b < BB; ++b)
            t_tile[j][b * DIN + lane] = __float2bfloat16(acc[b >> 2][b & 3]);
        t_tile[j][BB * DIN + lane] = __float2bfloat16(xself);
    }
    __syncthreads();

    // ---- phase 2: MFMA 16x16x32 bf16, K = 1984 (62 steps) over 16 waves ----
    const int m = lane & 15;
    const int q = lane >> 4;
    int kk0, nsteps, col_base, kpart;
    if (DOUT == 64) {
        kpart = wv >> 2;                 // 0..3
        col_base = (wv & 3) * 16;
        kk0    = (kpart <= 1) ? kpart * 16 : (kpart == 2 ? 32 : 47);
        nsteps = (kpart <= 1) ? 16 : 15;
    } else {
        kpart = wv;                      // 0..15
        col_base = 0;
        kk0    = (kpart < 14) ? kpart * 4 : (kpart == 14 ? 56 : 59);
        nsteps = (kpart < 14) ? 4 : 3;
    }
    const __hip_bfloat16* arow = &t_tile[m][q * 8];
    const short* brow = Wt + (size_t)(col_base + m) * KTOT + q * 8;

    floatx4 acc0 = {0.f, 0.f, 0.f, 0.f};
    floatx4 acc1 = {0.f, 0.f, 0.f, 0.f};
    int s = 0;
    for (; s + 2 <= nsteps; s += 2) {
        const int kk = kk0 + s;
        short8 a0 = *reinterpret_cast<const short8*>(arow + kk * 32);
        short8 b0 = *reinterpret_cast<const short8*>(brow + kk * 32);
        short8 a1 = *reinterpret_cast<const short8*>(arow + (kk + 1) * 32);
        short8 b1 = *reinterpret_cast<const short8*>(brow + (kk + 1) * 32);
        acc0 = __builtin_amdgcn_mfma_f32_16x16x32_bf16(a0, b0, acc0, 0, 0, 0);
        acc1 = __builtin_amdgcn_mfma_f32_16x16x32_bf16(a1, b1, acc1, 0, 0, 0);
    }
    if (s < nsteps) {
        const int kk = kk0 + s;
        short8 a0 = *reinterpret_cast<const short8*>(arow + kk * 32);
        short8 b0 = *reinterpret_cast<const short8*>(brow + kk * 32);
        acc0 = __builtin_amdgcn_mfma_f32_16x16x32_bf16(a0, b0, acc0, 0, 0, 0);
    }
    floatx4 P = acc0 + acc1;

    __syncthreads();                       // all t_tile reads done
    float* red = (float*)smem_raw;         // reuse LDS; stride-6 layout, 2-way max

    if (DOUT == 64) {
        // 4 K-parts per col group; parts 1..3 write, part 0 reduces
        if (kpart > 0) {
            const int slot = (wv & 3) * 3 + (kpart - 1);   // 0..11
            const int off = (slot * 64 + lane) * 6;
            red[off] = P[0]; red[off + 1] = P[1]; red[off + 2] = P[2]; red[off + 3] = P[3];
        }
        __syncthreads();
        if (kpart == 0) {
#pragma unroll
            for (int t = 0; t < 3; ++t) {
                const int off = (((wv & 3) * 3 + t) * 64 + lane) * 6;
                P[0] += red[off]; P[1] += red[off + 1];
                P[2] += red[off + 2]; P[3] += red[off + 3];
            }
            const int o = col_base + m;
            const float bi = bias[o];
#pragma unroll
            for (int r = 0; r < 4; ++r) {
                const int n = node0 + q * 4 + r;
                float v = P[r] + bi;
                if (RELU) {
                    v = fmaxf(v, 0.f);
                    reinterpret_cast<__hip_bfloat16*>(outp)[(size_t)n * DOUT + o] =
                        __float2bfloat16(v);
                } else {
                    reinterpret_cast<float*>(outp)[(size_t)n * DOUT + o] = v;
                }
            }
        }
    } else {
        if (kpart > 0) {
            const int off = ((kpart - 1) * 64 + lane) * 6;
            red[off] = P[0]; red[off + 1] = P[1]; red[off + 2] = P[2]; red[off + 3] = P[3];
        }
        __syncthreads();
        if (kpart == 0) {
#pragma unroll
            for (int w = 0; w < 15; ++w) {
                const int off = (w * 64 + lane) * 6;
                P[0] += red[off]; P[1] += red[off + 1];
                P[2] += red[off + 2]; P[3] += red[off + 3];
            }
            if (m < DOUT) {
                const int o = m;
                const float bi = bias[o];
#pragma unroll
                for (int r = 0; r < 4; ++r) {
                    const int n = node0 + q * 4 + r;
                    reinterpret_cast<float*>(outp)[(size_t)n * DOUT + o] = P[r] + bi;
                }
            }
        }
    }
}

// ---------------- log_softmax over C=8 ----------------
__global__ void k_lsm(const float* __restrict__ pre, float* __restrict__ out) {
    int n = blockIdx.x * 256 + threadIdx.x;
    if (n < NN) {
        float v[8];
        float mx = -1e30f;
#pragma unroll
        for (int c = 0; c < 8; ++c) { v[c] = pre[n * 8 + c]; mx = fmaxf(mx, v[c]); }
        float s = 0.f;
#pragma unroll
        for (int c = 0; c < 8; ++c) s += expf(v[c] - mx);
        float ls = logf(s);
#pragma unroll
        for (int c = 0; c < 8; ++c) out[n * 8 + c] = v[c] - mx - ls;
    }
}

// ---------------- launch ----------------
extern "C" void kernel_launch(void* const* d_in, const int* in_sizes, int n_in,
                              void* d_out, int out_size, void* d_ws, size_t ws_size,
                              hipStream_t stream) {
    const float* x     = (const float*)d_in[0];
    const int*   eidx  = (const int*)d_in[1];
    const int*   etype = (const int*)d_in[2];
    const float* bases0 = (const float*)d_in[3];
    const float* comp0  = (const float*)d_in[4];
    const float* root0  = (const float*)d_in[5];
    const float* bias0  = (const float*)d_in[6];
    const float* bases1 = (const float*)d_in[7];
    const float* comp1  = (const float*)d_in[8];
    const float* root1  = (const float*)d_in[9];
    const float* bias1  = (const float*)d_in[10];
    const float* bases2 = (const float*)d_in[11];
    const float* comp2  = (const float*)d_in[12];
    const float* root2  = (const float*)d_in[13];
    const float* bias2  = (const float*)d_in[14];
    const int* srcp = eidx;
    const int* dstp = eidx + EE;

    char* p = (char*)d_ws;
    auto carve = [&](size_t bytes) -> char* {
        char* r = p;
        p += (bytes + 255) & ~(size_t)255;
        return r;
    };
    int*  cnt    = (int*)carve((size_t)NN * RR * sizeof(int));   // 10 MB
    int*  dcount = (int*)carve((size_t)NN * sizeof(int));
    int*  cursor = (int*)carve((size_t)NN * sizeof(int));
    int*  doff   = (int*)carve((size_t)NN * sizeof(int));
    int*  bsum   = (int*)carve(256 * sizeof(int));
    int4* epack  = (int4*)carve((size_t)EE * sizeof(int4));      // 16 MB
    __hip_bfloat16* h0 = (__hip_bfloat16*)carve((size_t)NN * DIN * 2);
    __hip_bfloat16* h1 = (__hip_bfloat16*)carve((size_t)NN * DIN * 2);
    __hip_bfloat16* h2 = (__hip_bfloat16*)carve((size_t)NN * DIN * 2);
    float* pre = (float*)carve((size_t)NN * 8 * sizeof(float));
    short* wtA = (short*)carve((size_t)144 * KTOT * sizeof(short));  // 3 layers stacked
    float* cpA = (float*)carve((size_t)3 * RR * CPAD * sizeof(float));

    // cnt, dcount, cursor are adjacent in the carve order -> one memset
    hipMemsetAsync(cnt, 0, (size_t)NN * (RR + 2) * sizeof(int) + 512, stream);

    const int EB = (EE + 255) / 256;   // 3907
    const int NB = (NN + 255) / 256;   // 196
    k_hist<<<EB, 256, 0, stream>>>(dstp, etype, cnt, dcount);
    k_scan1<<<NB, 256, 0, stream>>>(dcount, doff, bsum);
    k_scan2<<<1, 256, 0, stream>>>(bsum, NB);
    k_scan3<<<NB, 256, 0, stream>>>(doff, bsum);
    k_scatter<<<EB, 256, 0, stream>>>(srcp, dstp, etype, cnt, doff, cursor, epack);
    k_cast_x<<<(NN * DIN + 255) / 256, 256, 0, stream>>>(x, h0);
    k_prep_comp3<<<(3 * RR * CPAD + 255) / 256, 256, 0, stream>>>(comp0, comp1, comp2, cpA);
    k_prep_w3<<<(144 * KTOT + 255) / 256, 256, 0, stream>>>(bases0, root0, bases1, root1,
                                                            bases2, root2, wtA);

    short* wt0 = wtA;
    short* wt1 = wtA + (size_t)64 * KTOT;
    short* wt2 = wtA + (size_t)128 * KTOT;
    float* cp0 = cpA;
    float* cp1 = cpA + RR * CPAD;
    float* cp2 = cpA + 2 * RR * CPAD;

    const int NF = NN / NBW;   // 3125 (exact)
    k_fused<64, true ><<<NF, 1024, 0, stream>>>(h0, epack, doff, dcount, cp0, wt0, bias0, (void*)h1);
    k_fused<64, true ><<<NF, 1024, 0, stream>>>(h1, epack, doff, dcount, cp1, wt1, bias1, (void*)h2);
    k_fused<8,  false><<<NF, 1024, 0, stream>>>(h2, epack, doff, dcount, cp2, wt2, bias2, (void*)pre);
    k_lsm<<<NB, 256, 0, stream>>>(pre, (float*)d_out);
}

// Round 7
// 596.918 us; speedup vs baseline: 1.8832x; 1.0262x over previous
//
#include <hip/hip_runtime.h>
#include <hip/hip_bf16.h>
#include <stdint.h>

// Problem constants (fixed by the reference)
#define NN   50000
#define RR   50
#define BB   30
#define DIN  64
#define EE   1000000
#define KTOT (BB*DIN + DIN)   // 1984 = 62*32
#define NBW  16               // nodes per workgroup; 50000 = 3125*16 exactly
#define ROWE (KTOT + 8)       // padded LDS row: 1992 elems (3984 B)
#define CPAD 32               // comp row padded 30 -> 32 floats

typedef __attribute__((ext_vector_type(8))) short short8;
typedef __attribute__((ext_vector_type(4))) float floatx4;

#define RFL(x) __builtin_amdgcn_readfirstlane(x)

// ---------------- preprocessing: counting sort of edges by dst ----------------

__global__ void k_hist(const int* __restrict__ dst, const int* __restrict__ et,
                       int* __restrict__ cnt, int* __restrict__ dcount) {
    int e = blockIdx.x * 256 + threadIdx.x;
    if (e < EE) {
        int d = dst[e], r = et[e];
        atomicAdd(&cnt[d * RR + r], 1);
        atomicAdd(&dcount[d], 1);
    }
}

__global__ void k_scan1(const int* __restrict__ dcount, int* __restrict__ doff,
                        int* __restrict__ bsum) {
    __shared__ int sh[256];
    int t = threadIdx.x;
    int i = blockIdx.x * 256 + t;
    int v = (i < NN) ? dcount[i] : 0;
    sh[t] = v;
    __syncthreads();
    for (int s = 1; s < 256; s <<= 1) {
        int add = (t >= s) ? sh[t - s] : 0;
        __syncthreads();
        sh[t] += add;
        __syncthreads();
    }
    int incl = sh[t];
    if (i < NN) doff[i] = incl - v;
    if (t == 255) bsum[blockIdx.x] = incl;
}

__global__ void k_scan2(int* __restrict__ bsum, int nbv) {
    __shared__ int sh[256];
    int t = threadIdx.x;
    int v = (t < nbv) ? bsum[t] : 0;
    sh[t] = v;
    __syncthreads();
    for (int s = 1; s < 256; s <<= 1) {
        int add = (t >= s) ? sh[t - s] : 0;
        __syncthreads();
        sh[t] += add;
        __syncthreads();
    }
    if (t < nbv) bsum[t] = sh[t] - v;
}

__global__ void k_scan3(int* __restrict__ doff, const int* __restrict__ bsum) {
    int i = blockIdx.x * 256 + threadIdx.x;
    if (i < NN) doff[i] += bsum[blockIdx.x];
}

__global__ void k_scatter(const int* __restrict__ src, const int* __restrict__ dst,
                          const int* __restrict__ et, const int* __restrict__ cnt,
                          const int* __restrict__ doff, int* __restrict__ cursor,
                          int4* __restrict__ epack) {
    int e = blockIdx.x * 256 + threadIdx.x;
    if (e < EE) {
        int d = dst[e], r = et[e], s = src[e];
        int p = doff[d] + atomicAdd(&cursor[d], 1);
        float a = 1.0f / (float)cnt[d * RR + r];
        epack[p] = make_int4(s, r, __float_as_int(a), 0);
    }
}

__global__ void k_cast_x(const float* __restrict__ x, __hip_bfloat16* __restrict__ h) {
    int i = blockIdx.x * 256 + threadIdx.x;
    if (i < NN * DIN) h[i] = __float2bfloat16(x[i]);
}

// all 3 layers' comp [R,30] fp32 -> padded [3][R,32] fp32
__global__ void k_prep_comp3(const float* __restrict__ c0, const float* __restrict__ c1,
                             const float* __restrict__ c2, float* __restrict__ cp) {
    int idx = blockIdx.x * 256 + threadIdx.x;
    if (idx < 3 * RR * CPAD) {
        int l = idx / (RR * CPAD);
        int rem = idx - l * (RR * CPAD);
        int r = rem / CPAD, i = rem - r * CPAD;
        const float* c = (l == 0) ? c0 : (l == 1) ? c1 : c2;
        cp[idx] = (i < BB) ? c[r * BB + i] : 0.f;
    }
}

// all 3 layers' transposed bf16 weights:
// wt rows [0,64): layer0; [64,128): layer1; [128,144): layer2 (dout=8, 16 padded rows)
__global__ void k_prep_w3(const float* __restrict__ b0, const float* __restrict__ r0,
                          const float* __restrict__ b1, const float* __restrict__ r1,
                          const float* __restrict__ b2, const float* __restrict__ r2,
                          short* __restrict__ wt) {
    int idx = blockIdx.x * 256 + threadIdx.x;
    if (idx >= 144 * KTOT) return;
    int row = idx / KTOT, k = idx - row * KTOT;
    const float* bs; const float* rt; int o, dout;
    if (row < 64)       { bs = b0; rt = r0; o = row;        dout = 64; }
    else if (row < 128) { bs = b1; rt = r1; o = row - 64;   dout = 64; }
    else                { bs = b2; rt = r2; o = row - 128;  dout = 8;  }
    float v = 0.f;
    if (o < dout)
        v = (k < BB * DIN) ? bs[k * dout + o] : rt[(k - BB * DIN) * dout + o];
    __hip_bfloat16 hb = __float2bfloat16(v);
    wt[idx] = *reinterpret_cast<const short*>(&hb);
}

// ---------------- fused per-layer kernel ----------------
// 1024 threads = 16 waves, 2 blocks/CU (LDS-capped) -> 32 waves/CU.
// Phase 1: wave wv owns node wv; 4-edge chunks in a 3-stage pipeline:
//   records chunk c+2 prefetched via uniform s_load (SGPR-resident, zero VGPR),
//   x-gathers chunk c+1 in flight during chunk c's FMAs.
//   (Single chain, minimal VGPR state — R5's dual-chain variant spilled.)
// Phase 2: 16 waves = 4 col-tiles x 4 K-parts (DOUT=64) or 16 K-parts (DOUT=8);
//   partials reduced through LDS with stride-6 layout.
template <int DOUT, bool RELU>
__global__ __launch_bounds__(1024, 8)
void k_fused(const __hip_bfloat16* __restrict__ xin,
             const int4* __restrict__ epack,
             const int* __restrict__ doff, const int* __restrict__ dcount,
             const float* __restrict__ compP,    // [R, 32] fp32 padded
             const short* __restrict__ Wt,       // [DPAD][KTOT] bf16 (transposed)
             const float* __restrict__ bias,     // [DOUT]
             void* __restrict__ outp) {
    __shared__ __align__(16) char smem_raw[NBW * ROWE * 2];   // 63744 B
    auto t_tile = reinterpret_cast<__hip_bfloat16(*)[ROWE]>(smem_raw);
    const int tid  = threadIdx.x;
    const int lane = tid & 63;
    const int wv   = RFL(tid >> 6);          // 0..15
    const int node0 = blockIdx.x * NBW;

    // ---- phase 1: one node per wave, pipelined 4-edge chunks ----
    {
        const int j = wv;
        const int n = node0 + j;              // always < NN (50000 = 3125*16)
        floatx4 acc[8];
#pragma unroll
        for (int u = 0; u < 8; ++u) acc[u] = (floatx4){0.f, 0.f, 0.f, 0.f};
        const int beg = RFL(doff[n]), cnt = RFL(dcount[n]);
        const int nch = cnt >> 2;             // full 4-edge chunks

        if (nch > 0) {
            // current-chunk records (SGPRs)
            int4 cr0 = epack[beg + 0], cr1 = epack[beg + 1];
            int4 cr2 = epack[beg + 2], cr3 = epack[beg + 3];
            // gathers for chunk 0 (in flight)
            float g0 = __bfloat162float(xin[RFL(cr0.x) * DIN + lane]);
            float g1 = __bfloat162float(xin[RFL(cr1.x) * DIN + lane]);
            float g2 = __bfloat162float(xin[RFL(cr2.x) * DIN + lane]);
            float g3 = __bfloat162float(xin[RFL(cr3.x) * DIN + lane]);
            // next-chunk records (clamped)
            const int b1 = beg + ((1 < nch) ? 4 : 0);
            int4 nr0 = epack[b1 + 0], nr1 = epack[b1 + 1];
            int4 nr2 = epack[b1 + 2], nr3 = epack[b1 + 3];

            for (int c = 0; c < nch; ++c) {
                // prefetch records for chunk c+2 (clamped; uniform s_load)
                const int cc = (c + 2 < nch) ? (c + 2) : (nch - 1);
                const int bp = beg + 4 * cc;
                int4 p0 = epack[bp + 0], p1 = epack[bp + 1];
                int4 p2 = epack[bp + 2], p3 = epack[bp + 3];
                // issue gathers for chunk c+1 (records already in SGPRs)
                float h0 = __bfloat162float(xin[RFL(nr0.x) * DIN + lane]);
                float h1 = __bfloat162float(xin[RFL(nr1.x) * DIN + lane]);
                float h2 = __bfloat162float(xin[RFL(nr2.x) * DIN + lane]);
                float h3 = __bfloat162float(xin[RFL(nr3.x) * DIN + lane]);
                // FMA chunk c (waits only on chunk c's gathers: vmcnt(4))
                {
                    const float a0 = __int_as_float(RFL(cr0.z));
                    const floatx4* q0 = (const floatx4*)(compP + RFL(cr0.y) * CPAD);
                    const float xv0 = g0 * a0;
                    const floatx4 w0 = {xv0, xv0, xv0, xv0};
#pragma unroll
                    for (int u = 0; u < 8; ++u) acc[u] = q0[u] * w0 + acc[u];
                    const float a1 = __int_as_float(RFL(cr1.z));
                    const floatx4* q1 = (const floatx4*)(compP + RFL(cr1.y) * CPAD);
                    const float xv1 = g1 * a1;
                    const floatx4 w1 = {xv1, xv1, xv1, xv1};
#pragma unroll
                    for (int u = 0; u < 8; ++u) acc[u] = q1[u] * w1 + acc[u];
                    const float a2 = __int_as_float(RFL(cr2.z));
                    const floatx4* q2 = (const floatx4*)(compP + RFL(cr2.y) * CPAD);
                    const float xv2 = g2 * a2;
                    const floatx4 w2 = {xv2, xv2, xv2, xv2};
#pragma unroll
                    for (int u = 0; u < 8; ++u) acc[u] = q2[u] * w2 + acc[u];
                    const float a3 = __int_as_float(RFL(cr3.z));
                    const floatx4* q3 = (const floatx4*)(compP + RFL(cr3.y) * CPAD);
                    const float xv3 = g3 * a3;
                    const floatx4 w3 = {xv3, xv3, xv3, xv3};
#pragma unroll
                    for (int u = 0; u < 8; ++u) acc[u] = q3[u] * w3 + acc[u];
                }
                // rotate pipeline
                cr0 = nr0; cr1 = nr1; cr2 = nr2; cr3 = nr3;
                nr0 = p0;  nr1 = p1;  nr2 = p2;  nr3 = p3;
                g0 = h0; g1 = h1; g2 = h2; g3 = h3;
            }
        }
        // tail edges [nch*4, cnt): serial
        for (int e = nch * 4; e < cnt; ++e) {
            int4 ep = epack[beg + e];
            const int s = RFL(ep.x), r = RFL(ep.y);
            const float a = __int_as_float(RFL(ep.z));
            const float xv = __bfloat162float(xin[s * DIN + lane]) * a;
            const floatx4* c = (const floatx4*)(compP + r * CPAD);
            const floatx4 w = {xv, xv, xv, xv};
#pragma unroll
            for (int u = 0; u < 8; ++u) acc[u] = c[u] * w + acc[u];
        }
        const float xself = __bfloat162float(xin[n * DIN + lane]);
#pragma unroll
        for (int b = 0; b < BB; ++b)
            t_tile[j][b * DIN + lane] = __float2bfloat16(acc[b >> 2][b & 3]);
        t_tile[j][BB * DIN + lane] = __float2bfloat16(xself);
    }
    __syncthreads();

    // ---- phase 2: MFMA 16x16x32 bf16, K = 1984 (62 steps) over 16 waves ----
    const int m = lane & 15;
    const int q = lane >> 4;
    int kk0, nsteps, col_base, kpart;
    if (DOUT == 64) {
        kpart = wv >> 2;                 // 0..3
        col_base = (wv & 3) * 16;
        kk0    = (kpart <= 1) ? kpart * 16 : (kpart == 2 ? 32 : 47);
        nsteps = (kpart <= 1) ? 16 : 15;
    } else {
        kpart = wv;                      // 0..15
        col_base = 0;
        kk0    = (kpart < 14) ? kpart * 4 : (kpart == 14 ? 56 : 59);
        nsteps = (kpart < 14) ? 4 : 3;
    }
    const __hip_bfloat16* arow = &t_tile[m][q * 8];
    const short* brow = Wt + (size_t)(col_base + m) * KTOT + q * 8;

    floatx4 acc0 = {0.f, 0.f, 0.f, 0.f};
    floatx4 acc1 = {0.f, 0.f, 0.f, 0.f};
    int s = 0;
    for (; s + 2 <= nsteps; s += 2) {
        const int kk = kk0 + s;
        short8 a0 = *reinterpret_cast<const short8*>(arow + kk * 32);
        short8 b0 = *reinterpret_cast<const short8*>(brow + kk * 32);
        short8 a1 = *reinterpret_cast<const short8*>(arow + (kk + 1) * 32);
        short8 b1 = *reinterpret_cast<const short8*>(brow + (kk + 1) * 32);
        acc0 = __builtin_amdgcn_mfma_f32_16x16x32_bf16(a0, b0, acc0, 0, 0, 0);
        acc1 = __builtin_amdgcn_mfma_f32_16x16x32_bf16(a1, b1, acc1, 0, 0, 0);
    }
    if (s < nsteps) {
        const int kk = kk0 + s;
        short8 a0 = *reinterpret_cast<const short8*>(arow + kk * 32);
        short8 b0 = *reinterpret_cast<const short8*>(brow + kk * 32);
        acc0 = __builtin_amdgcn_mfma_f32_16x16x32_bf16(a0, b0, acc0, 0, 0, 0);
    }
    floatx4 P = acc0 + acc1;

    __syncthreads();                       // all t_tile reads done
    float* red = (float*)smem_raw;         // reuse LDS; stride-6 layout

    if (DOUT == 64) {
        // 4 K-parts per col group; parts 1..3 write, part 0 reduces
        if (kpart > 0) {
            const int slot = (wv & 3) * 3 + (kpart - 1);   // 0..11
            const int off = (slot * 64 + lane) * 6;
            red[off] = P[0]; red[off + 1] = P[1]; red[off + 2] = P[2]; red[off + 3] = P[3];
        }
        __syncthreads();
        if (kpart == 0) {
#pragma unroll
            for (int t = 0; t < 3; ++t) {
                const int off = (((wv & 3) * 3 + t) * 64 + lane) * 6;
                P[0] += red[off]; P[1] += red[off + 1];
                P[2] += red[off + 2]; P[3] += red[off + 3];
            }
            const int o = col_base + m;
            const float bi = bias[o];
#pragma unroll
            for (int r = 0; r < 4; ++r) {
                const int n = node0 + q * 4 + r;
                float v = P[r] + bi;
                if (RELU) {
                    v = fmaxf(v, 0.f);
                    reinterpret_cast<__hip_bfloat16*>(outp)[(size_t)n * DOUT + o] =
                        __float2bfloat16(v);
                } else {
                    reinterpret_cast<float*>(outp)[(size_t)n * DOUT + o] = v;
                }
            }
        }
    } else {
        if (kpart > 0) {
            const int off = ((kpart - 1) * 64 + lane) * 6;
            red[off] = P[0]; red[off + 1] = P[1]; red[off + 2] = P[2]; red[off + 3] = P[3];
        }
        __syncthreads();
        if (kpart == 0) {
#pragma unroll
            for (int w = 0; w < 15; ++w) {
                const int off = (w * 64 + lane) * 6;
                P[0] += red[off]; P[1] += red[off + 1];
                P[2] += red[off + 2]; P[3] += red[off + 3];
            }
            if (m < DOUT) {
                const int o = m;
                const float bi = bias[o];
#pragma unroll
                for (int r = 0; r < 4; ++r) {
                    const int n = node0 + q * 4 + r;
                    reinterpret_cast<float*>(outp)[(size_t)n * DOUT + o] = P[r] + bi;
                }
            }
        }
    }
}

// ---------------- log_softmax over C=8 ----------------
__global__ void k_lsm(const float* __restrict__ pre, float* __restrict__ out) {
    int n = blockIdx.x * 256 + threadIdx.x;
    if (n < NN) {
        float v[8];
        float mx = -1e30f;
#pragma unroll
        for (int c = 0; c < 8; ++c) { v[c] = pre[n * 8 + c]; mx = fmaxf(mx, v[c]); }
        float s = 0.f;
#pragma unroll
        for (int c = 0; c < 8; ++c) s += expf(v[c] - mx);
        float ls = logf(s);
#pragma unroll
        for (int c = 0; c < 8; ++c) out[n * 8 + c] = v[c] - mx - ls;
    }
}

// ---------------- launch ----------------
extern "C" void kernel_launch(void* const* d_in, const int* in_sizes, int n_in,
                              void* d_out, int out_size, void* d_ws, size_t ws_size,
                              hipStream_t stream) {
    const float* x     = (const float*)d_in[0];
    const int*   eidx  = (const int*)d_in[1];
    const int*   etype = (const int*)d_in[2];
    const float* bases0 = (const float*)d_in[3];
    const float* comp0  = (const float*)d_in[4];
    const float* root0  = (const float*)d_in[5];
    const float* bias0  = (const float*)d_in[6];
    const float* bases1 = (const float*)d_in[7];
    const float* comp1  = (const float*)d_in[8];
    const float* root1  = (const float*)d_in[9];
    const float* bias1  = (const float*)d_in[10];
    const float* bases2 = (const float*)d_in[11];
    const float* comp2  = (const float*)d_in[12];
    const float* root2  = (const float*)d_in[13];
    const float* bias2  = (const float*)d_in[14];
    const int* srcp = eidx;
    const int* dstp = eidx + EE;

    char* p = (char*)d_ws;
    auto carve = [&](size_t bytes) -> char* {
        char* r = p;
        p += (bytes + 255) & ~(size_t)255;
        return r;
    };
    int*  cnt    = (int*)carve((size_t)NN * RR * sizeof(int));   // 10 MB
    int*  dcount = (int*)carve((size_t)NN * sizeof(int));
    int*  cursor = (int*)carve((size_t)NN * sizeof(int));
    int*  doff   = (int*)carve((size_t)NN * sizeof(int));
    int*  bsum   = (int*)carve(256 * sizeof(int));
    int4* epack  = (int4*)carve((size_t)EE * sizeof(int4));      // 16 MB
    __hip_bfloat16* h0 = (__hip_bfloat16*)carve((size_t)NN * DIN * 2);
    __hip_bfloat16* h1 = (__hip_bfloat16*)carve((size_t)NN * DIN * 2);
    __hip_bfloat16* h2 = (__hip_bfloat16*)carve((size_t)NN * DIN * 2);
    float* pre = (float*)carve((size_t)NN * 8 * sizeof(float));
    short* wtA = (short*)carve((size_t)144 * KTOT * sizeof(short));  // 3 layers stacked
    float* cpA = (float*)carve((size_t)3 * RR * CPAD * sizeof(float));

    // cnt, dcount, cursor are adjacent in the carve order -> one memset
    hipMemsetAsync(cnt, 0, (size_t)NN * (RR + 2) * sizeof(int) + 512, stream);

    const int EB = (EE + 255) / 256;   // 3907
    const int NB = (NN + 255) / 256;   // 196
    k_hist<<<EB, 256, 0, stream>>>(dstp, etype, cnt, dcount);
    k_scan1<<<NB, 256, 0, stream>>>(dcount, doff, bsum);
    k_scan2<<<1, 256, 0, stream>>>(bsum, NB);
    k_scan3<<<NB, 256, 0, stream>>>(doff, bsum);
    k_scatter<<<EB, 256, 0, stream>>>(srcp, dstp, etype, cnt, doff, cursor, epack);
    k_cast_x<<<(NN * DIN + 255) / 256, 256, 0, stream>>>(x, h0);
    k_prep_comp3<<<(3 * RR * CPAD + 255) / 256, 256, 0, stream>>>(comp0, comp1, comp2, cpA);
    k_prep_w3<<<(144 * KTOT + 255) / 256, 256, 0, stream>>>(bases0, root0, bases1, root1,
                                                            bases2, root2, wtA);

    short* wt0 = wtA;
    short* wt1 = wtA + (size_t)64 * KTOT;
    short* wt2 = wtA + (size_t)128 * KTOT;
    float* cp0 = cpA;
    float* cp1 = cpA + RR * CPAD;
    float* cp2 = cpA + 2 * RR * CPAD;

    const int NF = NN / NBW;   // 3125 (exact)
    k_fused<64, true ><<<NF, 1024, 0, stream>>>(h0, epack, doff, dcount, cp0, wt0, bias0, (void*)h1);
    k_fused<64, true ><<<NF, 1024, 0, stream>>>(h1, epack, doff, dcount, cp1, wt1, bias1, (void*)h2);
    k_fused<8,  false><<<NF, 1024, 0, stream>>>(h2, epack, doff, dcount, cp2, wt2, bias2, (void*)pre);
    k_lsm<<<NB, 256, 0, stream>>>(pre, (float*)d_out);
}